// Round 1
// baseline (260.442 us; speedup 1.0000x reference)
//
#include <hip/hip_runtime.h>
#include <hip/hip_bf16.h>

// GCN forward, algebraically collapsed.
// Since there is NO nonlinearity between the two GCNConv layers and pooling is
// a mean, the whole graph part collapses to a weighted sum of node features:
//   g = (1/n) * ( (A^T u)^T X ) @ W1 @ W2 + (1/n)*(sum u)*b1 @ W2 + b2
// where A = D^{-1/2}(Adj+I)D^{-1/2}, u^T = 1^T A.
// Then the tiny MLP head: softmax(relu(g@Wd1+bd1)@Wd2+bd2).

#define D_IN 128
#define D_HID 256
#define D_DENSE 128

// ---- edge pass 1: weighted in-degree (targets = col) -----------------------
__global__ void k_deg(const int* __restrict__ col, const float* __restrict__ w,
                      float* __restrict__ deg, int E) {
    int e = blockIdx.x * blockDim.x + threadIdx.x;
    if (e < E) atomicAdd(&deg[col[e]], w[e]);
}

// ---- node pass: dinv = rsqrt(deg + 1 self-loop); u init = self-loop term ---
__global__ void k_dinv(const float* __restrict__ deg, float* __restrict__ dinv,
                       float* __restrict__ u, int n) {
    int i = blockIdx.x * blockDim.x + threadIdx.x;
    if (i < n) {
        float d = rsqrtf(deg[i] + 1.0f);   // deg>=1 always (self-loop weight 1)
        dinv[i] = d;
        u[i] = d * d;                      // self-loop contribution to u
    }
}

// ---- edge pass 2: u[r] += norm_e ------------------------------------------
__global__ void k_u(const int* __restrict__ row, const int* __restrict__ colv,
                    const float* __restrict__ w, const float* __restrict__ dinv,
                    float* __restrict__ u, int E) {
    int e = blockIdx.x * blockDim.x + threadIdx.x;
    if (e < E) {
        int r = row[e], c = colv[e];
        atomicAdd(&u[r], dinv[r] * w[e] * dinv[c]);
    }
}

// ---- node pass: wv init (self-loop term) + reduce sum(u) -------------------
__global__ void k_wv_init(const float* __restrict__ dinv, const float* __restrict__ u,
                          float* __restrict__ wv, float* __restrict__ S_u, int n) {
    int i = blockIdx.x * blockDim.x + threadIdx.x;
    float myu = 0.f;
    if (i < n) {
        float d = dinv[i];
        float ui = u[i];
        myu = ui;
        wv[i] = d * d * ui;                // self-loop contribution to A^T u
    }
    // block reduction of myu (blockDim = 256 = 4 waves)
    for (int off = 32; off > 0; off >>= 1) myu += __shfl_down(myu, off, 64);
    __shared__ float wsum[4];
    int lane = threadIdx.x & 63, wid = threadIdx.x >> 6;
    if (lane == 0) wsum[wid] = myu;
    __syncthreads();
    if (threadIdx.x == 0) atomicAdd(S_u, wsum[0] + wsum[1] + wsum[2] + wsum[3]);
}

// ---- edge pass 3: wv[r] += norm_e * u[c]  (wv = A^T u) ---------------------
__global__ void k_wv(const int* __restrict__ row, const int* __restrict__ colv,
                     const float* __restrict__ w, const float* __restrict__ dinv,
                     const float* __restrict__ u, float* __restrict__ wv, int E) {
    int e = blockIdx.x * blockDim.x + threadIdx.x;
    if (e < E) {
        int r = row[e], c = colv[e];
        atomicAdd(&wv[r], dinv[r] * w[e] * dinv[c] * u[c]);
    }
}

// ---- feature pass: s[k] = sum_i wv[i] * x[i,k] -----------------------------
__global__ void k_s(const float* __restrict__ x, const float* __restrict__ wv,
                    float* __restrict__ s, int n) {
    int k = threadIdx.x;                   // 0..127, column (coalesced)
    float acc = 0.f;
    for (int i = blockIdx.x; i < n; i += gridDim.x)
        acc += wv[i] * x[i * D_IN + k];
    atomicAdd(&s[k], acc);
}

// ---- dense head: single block, 256 threads ---------------------------------
__global__ void k_head(const float* __restrict__ s, const float* __restrict__ S_u,
                       const float* __restrict__ W1, const float* __restrict__ b1,
                       const float* __restrict__ W2, const float* __restrict__ b2,
                       const float* __restrict__ Wd1, const float* __restrict__ bd1,
                       const float* __restrict__ Wd2, const float* __restrict__ bd2,
                       float* __restrict__ out, float inv_n) {
    __shared__ float sh_s[D_IN];
    __shared__ float t1[D_HID];
    __shared__ float g[D_HID];
    __shared__ float z[D_DENSE];
    int t = threadIdx.x;
    if (t < D_IN) sh_s[t] = s[t];
    __syncthreads();

    float su = *S_u;
    // t1 = s @ W1 + (sum u) * b1        [256]
    float acc = 0.f;
    #pragma unroll 8
    for (int k = 0; k < D_IN; k++) acc += sh_s[k] * W1[k * D_HID + t];
    t1[t] = acc + su * b1[t];
    __syncthreads();

    // g = t1 @ W2 / n + b2              [256]
    acc = 0.f;
    #pragma unroll 8
    for (int k = 0; k < D_HID; k++) acc += t1[k] * W2[k * D_HID + t];
    g[t] = acc * inv_n + b2[t];
    __syncthreads();

    // z = relu(g @ Wd1 + bd1)           [128]
    if (t < D_DENSE) {
        acc = 0.f;
        #pragma unroll 8
        for (int k = 0; k < D_HID; k++) acc += g[k] * Wd1[k * D_DENSE + t];
        z[t] = fmaxf(acc + bd1[t], 0.f);
    }
    __syncthreads();

    // logits + softmax (2 classes) — trivial, thread 0
    if (t == 0) {
        float l0 = bd2[0], l1 = bd2[1];
        for (int k = 0; k < D_DENSE; k++) {
            l0 += z[k] * Wd2[k * 2 + 0];
            l1 += z[k] * Wd2[k * 2 + 1];
        }
        float m = fmaxf(l0, l1);
        float e0 = expf(l0 - m), e1 = expf(l1 - m);
        float inv = 1.0f / (e0 + e1);
        out[0] = e0 * inv;
        out[1] = e1 * inv;
    }
}

extern "C" void kernel_launch(void* const* d_in, const int* in_sizes, int n_in,
                              void* d_out, int out_size, void* d_ws, size_t ws_size,
                              hipStream_t stream) {
    const float* x   = (const float*)d_in[0];
    const int*   ei  = (const int*)  d_in[1];
    const float* w   = (const float*)d_in[2];
    const float* W1  = (const float*)d_in[3];
    const float* b1  = (const float*)d_in[4];
    const float* W2  = (const float*)d_in[5];
    const float* b2  = (const float*)d_in[6];
    const float* Wd1 = (const float*)d_in[7];
    const float* bd1 = (const float*)d_in[8];
    const float* Wd2 = (const float*)d_in[9];
    const float* bd2 = (const float*)d_in[10];
    float* out = (float*)d_out;

    const int N = in_sizes[0] / D_IN;      // 20000
    const int E = in_sizes[1] / 2;         // 640000
    const int* row = ei;
    const int* col = ei + E;

    // workspace layout (floats): [deg N][s 128][S_u 1][dinv N][u N][wv N]
    float* ws   = (float*)d_ws;
    float* deg  = ws;
    float* s    = ws + N;
    float* S_u  = ws + N + D_IN;
    float* dinv = ws + N + D_IN + 1;
    float* u    = dinv + N;
    float* wv   = u + N;

    // zero only what is accumulated into (deg, s, S_u); rest is fully written
    hipMemsetAsync(d_ws, 0, (size_t)(N + D_IN + 1) * sizeof(float), stream);

    int ge = (E + 255) / 256;
    int gn = (N + 255) / 256;

    k_deg<<<ge, 256, 0, stream>>>(col, w, deg, E);
    k_dinv<<<gn, 256, 0, stream>>>(deg, dinv, u, N);
    k_u<<<ge, 256, 0, stream>>>(row, col, w, dinv, u, E);
    k_wv_init<<<gn, 256, 0, stream>>>(dinv, u, wv, S_u, N);
    k_wv<<<ge, 256, 0, stream>>>(row, col, w, dinv, u, wv, E);
    k_s<<<256, D_IN, 0, stream>>>(x, wv, s, N);
    k_head<<<1, D_HID, 0, stream>>>(s, S_u, W1, b1, W2, b2, Wd1, bd1, Wd2, bd2,
                                    out, 1.0f / (float)N);
}

// Round 2
// 216.232 us; speedup vs baseline: 1.2045x; 1.2045x over previous
//
#include <hip/hip_runtime.h>
#include <hip/hip_bf16.h>

// GCN forward, algebraically collapsed (no nonlinearity between convs, mean pool):
//   g = (1/n) * ( (A^T u)^T X ) @ W1 @ W2 + (1/n)*(sum u)*(b1 @ W2) + b2
// where A = D^{-1/2}(Adj+I)D^{-1/2}, u^T = 1^T A.  Head: softmax(relu(g@Wd1+bd1)@Wd2+bd2).
//
// Round 2: (a) scatter targets padded to one node per 128B cache line to kill
// memory-side same-line atomic serialization; (b) head split into multi-block
// GEMV kernels (single-block k_head was 43us latency-bound on 512KB of weights).

#define D_IN 128
#define D_HID 256
#define D_DENSE 128

// ---- edge pass 1: weighted in-degree (targets = col) -----------------------
__global__ void k_deg(const int* __restrict__ col, const float* __restrict__ w,
                      float* __restrict__ deg, int E, int pad) {
    int e = blockIdx.x * blockDim.x + threadIdx.x;
    if (e < E) atomicAdd(&deg[col[e] * pad], w[e]);
}

// ---- node pass: dinv (dense) + u init (self-loop term, padded) -------------
__global__ void k_dinv(const float* __restrict__ deg, float* __restrict__ dinv,
                       float* __restrict__ u, int n, int pad) {
    int i = blockIdx.x * blockDim.x + threadIdx.x;
    if (i < n) {
        float d = rsqrtf(deg[i * pad] + 1.0f);   // +1: self-loop weight
        dinv[i] = d;
        u[i * pad] = d * d;                      // self-loop contribution to u
    }
}

// ---- edge pass 2: u[r] += dinv[r]*w*dinv[c] --------------------------------
__global__ void k_u(const int* __restrict__ row, const int* __restrict__ colv,
                    const float* __restrict__ w, const float* __restrict__ dinv,
                    float* __restrict__ u, int E, int pad) {
    int e = blockIdx.x * blockDim.x + threadIdx.x;
    if (e < E) {
        int r = row[e], c = colv[e];
        atomicAdd(&u[r * pad], dinv[r] * w[e] * dinv[c]);
    }
}

// ---- node pass: wv init (self-loop) + reduce sum(u) ------------------------
__global__ void k_wv_init(const float* __restrict__ dinv, const float* __restrict__ u,
                          float* __restrict__ wv, float* __restrict__ S_u, int n, int pad) {
    int i = blockIdx.x * blockDim.x + threadIdx.x;
    float myu = 0.f;
    if (i < n) {
        float d = dinv[i];
        float ui = u[i * pad];
        myu = ui;
        wv[i * pad] = d * d * ui;
    }
    for (int off = 32; off > 0; off >>= 1) myu += __shfl_down(myu, off, 64);
    __shared__ float wsum[4];
    int lane = threadIdx.x & 63, wid = threadIdx.x >> 6;
    if (lane == 0) wsum[wid] = myu;
    __syncthreads();
    if (threadIdx.x == 0) atomicAdd(S_u, wsum[0] + wsum[1] + wsum[2] + wsum[3]);
}

// ---- edge pass 3: wv[r] += dinv[r]*w*dinv[c] * u[c] ------------------------
__global__ void k_wv(const int* __restrict__ row, const int* __restrict__ colv,
                     const float* __restrict__ w, const float* __restrict__ dinv,
                     const float* __restrict__ u, float* __restrict__ wv, int E, int pad) {
    int e = blockIdx.x * blockDim.x + threadIdx.x;
    if (e < E) {
        int r = row[e], c = colv[e];
        atomicAdd(&wv[r * pad], dinv[r] * w[e] * dinv[c] * u[c * pad]);
    }
}

// ---- feature pass: s[k] = sum_i wv[i] * x[i,k] -----------------------------
__global__ void k_s(const float* __restrict__ x, const float* __restrict__ wv,
                    float* __restrict__ s, int n, int pad) {
    int t = threadIdx.x;        // 256 threads: 2 rows x 128 cols
    int k = t & 127;
    int half = t >> 7;
    float acc = 0.f;
    for (int i = blockIdx.x * 2 + half; i < n; i += gridDim.x * 2)
        acc += wv[i * pad] * x[i * D_IN + k];
    __shared__ float sh[128];
    if (half) sh[k] = acc;
    __syncthreads();
    if (!half) atomicAdd(&s[k * pad], acc + sh[k]);
}

// ---- head, stage 1: t1 = s@W1 + sum(u)*b1   (16 blocks x 256) --------------
__global__ void k_h1(const float* __restrict__ s, const float* __restrict__ S_u,
                     const float* __restrict__ W1, const float* __restrict__ b1,
                     float* __restrict__ t1, int pad) {
    int t = threadIdx.x, b = blockIdx.x;
    float acc = 0.f;
    #pragma unroll
    for (int kk = 0; kk < 8; kk++) {
        int k = b * 8 + kk;
        acc += s[k * pad] * W1[k * D_HID + t];
    }
    if (b == 0) acc += (*S_u) * b1[t];
    atomicAdd(&t1[t], acc);
}

// ---- head, stage 2: g_raw = t1@W2   (32 blocks x 256) ----------------------
__global__ void k_h2(const float* __restrict__ t1, const float* __restrict__ W2,
                     float* __restrict__ g_raw) {
    int t = threadIdx.x, b = blockIdx.x;
    float acc = 0.f;
    #pragma unroll
    for (int kk = 0; kk < 8; kk++) {
        int k = b * 8 + kk;
        acc += t1[k] * W2[k * D_HID + t];
    }
    atomicAdd(&g_raw[t], acc);
}

// ---- head, stage 3: z_raw = (g_raw/n + b2) @ Wd1   (16 blocks x 128) -------
__global__ void k_h3(const float* __restrict__ g_raw, const float* __restrict__ b2,
                     const float* __restrict__ Wd1, float* __restrict__ z_raw,
                     float inv_n) {
    int t = threadIdx.x, b = blockIdx.x;
    float acc = 0.f;
    #pragma unroll
    for (int kk = 0; kk < 16; kk++) {
        int k = b * 16 + kk;
        float gk = g_raw[k] * inv_n + b2[k];
        acc += gk * Wd1[k * D_DENSE + t];
    }
    atomicAdd(&z_raw[t], acc);
}

// ---- head, stage 4: relu, logits, softmax   (1 block x 128) ----------------
__global__ void k_h4(const float* __restrict__ z_raw, const float* __restrict__ bd1,
                     const float* __restrict__ Wd2, const float* __restrict__ bd2,
                     float* __restrict__ out) {
    int t = threadIdx.x;
    float zt = fmaxf(z_raw[t] + bd1[t], 0.f);
    float p0 = zt * Wd2[t * 2 + 0];
    float p1 = zt * Wd2[t * 2 + 1];
    for (int off = 32; off > 0; off >>= 1) {
        p0 += __shfl_down(p0, off, 64);
        p1 += __shfl_down(p1, off, 64);
    }
    __shared__ float s0[2], s1[2];
    int lane = t & 63, wid = t >> 6;
    if (lane == 0) { s0[wid] = p0; s1[wid] = p1; }
    __syncthreads();
    if (t == 0) {
        float l0 = s0[0] + s0[1] + bd2[0];
        float l1 = s1[0] + s1[1] + bd2[1];
        float m = fmaxf(l0, l1);
        float e0 = expf(l0 - m), e1 = expf(l1 - m);
        float inv = 1.0f / (e0 + e1);
        out[0] = e0 * inv;
        out[1] = e1 * inv;
    }
}

extern "C" void kernel_launch(void* const* d_in, const int* in_sizes, int n_in,
                              void* d_out, int out_size, void* d_ws, size_t ws_size,
                              hipStream_t stream) {
    const float* x   = (const float*)d_in[0];
    const int*   ei  = (const int*)  d_in[1];
    const float* w   = (const float*)d_in[2];
    const float* W1  = (const float*)d_in[3];
    const float* b1  = (const float*)d_in[4];
    const float* W2  = (const float*)d_in[5];
    const float* b2  = (const float*)d_in[6];
    const float* Wd1 = (const float*)d_in[7];
    const float* bd1 = (const float*)d_in[8];
    const float* Wd2 = (const float*)d_in[9];
    const float* bd2 = (const float*)d_in[10];
    float* out = (float*)d_out;

    const int N = in_sizes[0] / D_IN;      // 20000
    const int E = in_sizes[1] / 2;         // 640000
    const int* row = ei;
    const int* col = ei + E;

    // pick largest line-pad that fits the workspace (32 floats = 128B line)
    size_t ws_floats = ws_size / sizeof(float);
    int pad = 1;
    for (int p = 32; p >= 1; p >>= 1) {
        size_t need = (size_t)3 * N * p + N + (size_t)D_IN * p + 641;
        if (need <= ws_floats) { pad = p; break; }
    }

    // layout (floats): [deg_pad N*pad][s_pad 128*pad][t1 256][g_raw 256]
    //                  [z_raw 128][S_u 1][u_pad N*pad][wv_pad N*pad][dinv N]
    float* ws    = (float*)d_ws;
    float* deg   = ws;
    float* s     = deg + (size_t)N * pad;
    float* t1    = s + (size_t)D_IN * pad;
    float* g_raw = t1 + D_HID;
    float* z_raw = g_raw + D_HID;
    float* S_u   = z_raw + D_DENSE;
    float* u     = S_u + 1;
    float* wv    = u + (size_t)N * pad;
    float* dinv  = wv + (size_t)N * pad;

    // zero everything that is atomically accumulated (deg..S_u is contiguous)
    size_t zero_bytes = (size_t)((size_t)N * pad + (size_t)D_IN * pad + 641) * sizeof(float);
    hipMemsetAsync(d_ws, 0, zero_bytes, stream);

    int ge = (E + 255) / 256;
    int gn = (N + 255) / 256;

    k_deg<<<ge, 256, 0, stream>>>(col, w, deg, E, pad);
    k_dinv<<<gn, 256, 0, stream>>>(deg, dinv, u, N, pad);
    k_u<<<ge, 256, 0, stream>>>(row, col, w, dinv, u, E, pad);
    k_wv_init<<<gn, 256, 0, stream>>>(dinv, u, wv, S_u, N, pad);
    k_wv<<<ge, 256, 0, stream>>>(row, col, w, dinv, u, wv, E, pad);
    k_s<<<256, 256, 0, stream>>>(x, wv, s, N, pad);
    k_h1<<<16, D_HID, 0, stream>>>(s, S_u, W1, b1, t1, pad);
    k_h2<<<32, D_HID, 0, stream>>>(t1, W2, g_raw);
    k_h3<<<16, D_DENSE, 0, stream>>>(g_raw, b2, Wd1, z_raw, 1.0f / (float)N);
    k_h4<<<1, D_DENSE, 0, stream>>>(z_raw, bd1, Wd2, bd2, out);
}

// Round 3
// 214.089 us; speedup vs baseline: 1.2165x; 1.0100x over previous
//
#include <hip/hip_runtime.h>
#include <hip/hip_bf16.h>

// GCN forward, algebraically collapsed (no nonlinearity between convs, mean pool):
//   g = (1/n) * ( (A^T u)^T X ) @ W1 @ W2 + (1/n)*(sum u)*(b1 @ W2) + b2
// where A = D^{-1/2}(Adj+I)D^{-1/2}, u^T = 1^T A.  Head: softmax(relu(g@Wd1+bd1)@Wd2+bd2).
//
// Round 3: global fp32 atomics are write-through to memory-side units on MI355X
// (round-1 counter: WRITE_SIZE = 640K x 32B for each edge pass; ~15 G atomic/s).
// Replace all edge scatters with LDS-privatized histograms (ds_add_f32) +
// non-atomic per-block partials + fused fold kernels. N=20000 is covered in
// two 16384-float LDS ranges (64 KB static LDS, 2 blocks/CU on 160 KB).

#define D_IN 128
#define D_HID 256
#define D_DENSE 128
#define NB 16384      // LDS bin size (floats) = 64 KB
#define RSC 128       // scatter blocks == partial replica count
#define PS 128        // k_s partial blocks

// ---- privatized edge scatter ----------------------------------------------
// mode 0: partial[b][col[e]] += w[e]
// mode 1: partial[b][row[e]] += w[e]*dinv[col[e]]
// mode 2: partial[b][row[e]] += w[e]*dinv[col[e]]*u[col[e]]
__global__ __launch_bounds__(256) void k_scatter(
    const int* __restrict__ tgt, const int* __restrict__ src,
    const float* __restrict__ w, const float* __restrict__ dinv,
    const float* __restrict__ u, float* __restrict__ partial,
    int E, int N, int mode) {
    __shared__ float acc[NB];
    int per = (E + gridDim.x - 1) / gridDim.x;
    int e0 = blockIdx.x * per;
    int e1 = min(e0 + per, E);
    float* out = partial + (size_t)blockIdx.x * N;
    for (int base = 0; base < N; base += NB) {
        int lim = min(NB, N - base);
        for (int i = threadIdx.x; i < lim; i += 256) acc[i] = 0.f;
        __syncthreads();
        for (int e = e0 + threadIdx.x; e < e1; e += 256) {
            int t = tgt[e] - base;
            if ((unsigned)t < (unsigned)lim) {
                float v = w[e];
                if (mode != 0) {
                    int c = src[e];
                    float dc = dinv[c];
                    v *= (mode == 2) ? dc * u[c] : dc;
                }
                atomicAdd(&acc[t], v);     // LDS atomic (ds_add_f32)
            }
        }
        __syncthreads();
        for (int i = threadIdx.x; i < lim; i += 256) out[base + i] = acc[i];
        __syncthreads();
    }
}

// ---- fold partials + node math --------------------------------------------
__global__ void k_red_deg(const float* __restrict__ partial,
                          float* __restrict__ dinv, int N) {
    int i = blockIdx.x * 256 + threadIdx.x;
    if (i >= N) return;
    float s = 0.f;
    for (int r = 0; r < RSC; ++r) s += partial[(size_t)r * N + i];
    dinv[i] = rsqrtf(s + 1.0f);            // +1: self-loop weight
}

__global__ void k_red_u(const float* __restrict__ partial, const float* __restrict__ dinv,
                        float* __restrict__ u, float* __restrict__ S_u, int N) {
    int i = blockIdx.x * 256 + threadIdx.x;
    float ui = 0.f;
    if (i < N) {
        float s = 0.f;
        for (int r = 0; r < RSC; ++r) s += partial[(size_t)r * N + i];
        float d = dinv[i];
        ui = d * (s + d);                  // u = dinv*(p + dinv)  (self-loop dinv^2)
        u[i] = ui;
    }
    for (int off = 32; off > 0; off >>= 1) ui += __shfl_down(ui, off, 64);
    __shared__ float wsum[4];
    int lane = threadIdx.x & 63, wid = threadIdx.x >> 6;
    if (lane == 0) wsum[wid] = ui;
    __syncthreads();
    if (threadIdx.x == 0) atomicAdd(S_u, wsum[0] + wsum[1] + wsum[2] + wsum[3]);
}

__global__ void k_red_wv(const float* __restrict__ partial, const float* __restrict__ dinv,
                         const float* __restrict__ u, float* __restrict__ wv, int N) {
    int i = blockIdx.x * 256 + threadIdx.x;
    if (i >= N) return;
    float s = 0.f;
    for (int r = 0; r < RSC; ++r) s += partial[(size_t)r * N + i];
    float d = dinv[i];
    wv[i] = d * (s + d * u[i]);            // wv = dinv*(q + dinv*u)
}

// ---- feature pass: s_part[b][k] = sum_{i in block b} wv[i]*x[i,k] ----------
__global__ void k_s(const float* __restrict__ x, const float* __restrict__ wv,
                    float* __restrict__ s_part, int n) {
    int t = threadIdx.x;                   // 256 threads: 2 rows x 128 cols
    int k = t & 127, half = t >> 7;
    float acc = 0.f;
    for (int i = blockIdx.x * 2 + half; i < n; i += gridDim.x * 2)
        acc += wv[i] * x[i * D_IN + k];
    __shared__ float sh[128];
    if (half) sh[k] = acc;
    __syncthreads();
    if (!half) s_part[blockIdx.x * D_IN + k] = acc + sh[k];
}

__global__ void k_sred(const float* __restrict__ s_part, float* __restrict__ s) {
    int k = threadIdx.x;                   // 128 threads
    float acc = 0.f;
    for (int p = 0; p < PS; ++p) acc += s_part[p * D_IN + k];
    s[k] = acc;
}

// ---- head, stage 1: t1 = s@W1 + sum(u)*b1   (16 blocks x 256) --------------
__global__ void k_h1(const float* __restrict__ s, const float* __restrict__ S_u,
                     const float* __restrict__ W1, const float* __restrict__ b1,
                     float* __restrict__ t1) {
    int t = threadIdx.x, b = blockIdx.x;
    float acc = 0.f;
    #pragma unroll
    for (int kk = 0; kk < 8; kk++) {
        int k = b * 8 + kk;
        acc += s[k] * W1[k * D_HID + t];
    }
    if (b == 0) acc += (*S_u) * b1[t];
    atomicAdd(&t1[t], acc);
}

// ---- head, stage 2: g_raw = t1@W2   (32 blocks x 256) ----------------------
__global__ void k_h2(const float* __restrict__ t1, const float* __restrict__ W2,
                     float* __restrict__ g_raw) {
    int t = threadIdx.x, b = blockIdx.x;
    float acc = 0.f;
    #pragma unroll
    for (int kk = 0; kk < 8; kk++) {
        int k = b * 8 + kk;
        acc += t1[k] * W2[k * D_HID + t];
    }
    atomicAdd(&g_raw[t], acc);
}

// ---- head, stage 3: z_raw = (g_raw/n + b2) @ Wd1   (16 blocks x 128) -------
__global__ void k_h3(const float* __restrict__ g_raw, const float* __restrict__ b2,
                     const float* __restrict__ Wd1, float* __restrict__ z_raw,
                     float inv_n) {
    int t = threadIdx.x, b = blockIdx.x;
    float acc = 0.f;
    #pragma unroll
    for (int kk = 0; kk < 16; kk++) {
        int k = b * 16 + kk;
        float gk = g_raw[k] * inv_n + b2[k];
        acc += gk * Wd1[k * D_DENSE + t];
    }
    atomicAdd(&z_raw[t], acc);
}

// ---- head, stage 4: relu, logits, softmax   (1 block x 128) ----------------
__global__ void k_h4(const float* __restrict__ z_raw, const float* __restrict__ bd1,
                     const float* __restrict__ Wd2, const float* __restrict__ bd2,
                     float* __restrict__ out) {
    int t = threadIdx.x;
    float zt = fmaxf(z_raw[t] + bd1[t], 0.f);
    float p0 = zt * Wd2[t * 2 + 0];
    float p1 = zt * Wd2[t * 2 + 1];
    for (int off = 32; off > 0; off >>= 1) {
        p0 += __shfl_down(p0, off, 64);
        p1 += __shfl_down(p1, off, 64);
    }
    __shared__ float s0[2], s1[2];
    int lane = t & 63, wid = t >> 6;
    if (lane == 0) { s0[wid] = p0; s1[wid] = p1; }
    __syncthreads();
    if (t == 0) {
        float l0 = s0[0] + s0[1] + bd2[0];
        float l1 = s1[0] + s1[1] + bd2[1];
        float m = fmaxf(l0, l1);
        float e0 = expf(l0 - m), e1 = expf(l1 - m);
        float inv = 1.0f / (e0 + e1);
        out[0] = e0 * inv;
        out[1] = e1 * inv;
    }
}

extern "C" void kernel_launch(void* const* d_in, const int* in_sizes, int n_in,
                              void* d_out, int out_size, void* d_ws, size_t ws_size,
                              hipStream_t stream) {
    const float* x   = (const float*)d_in[0];
    const int*   ei  = (const int*)  d_in[1];
    const float* w   = (const float*)d_in[2];
    const float* W1  = (const float*)d_in[3];
    const float* b1  = (const float*)d_in[4];
    const float* W2  = (const float*)d_in[5];
    const float* b2  = (const float*)d_in[6];
    const float* Wd1 = (const float*)d_in[7];
    const float* bd1 = (const float*)d_in[8];
    const float* Wd2 = (const float*)d_in[9];
    const float* bd2 = (const float*)d_in[10];
    float* out = (float*)d_out;

    const int N = in_sizes[0] / D_IN;      // 20000
    const int E = in_sizes[1] / 2;         // 640000
    const int* row = ei;
    const int* col = ei + E;

    // layout (floats): [S_u 1][t1 256][g_raw 256][z_raw 128]  <- zeroed (641)
    //                  [dinv N][u N][wv N][s 128][s_part PS*128][partial RSC*N]
    float* ws    = (float*)d_ws;
    float* S_u   = ws;
    float* t1    = ws + 1;
    float* g_raw = t1 + D_HID;
    float* z_raw = g_raw + D_HID;
    float* dinv  = z_raw + D_DENSE;        // ws + 641
    float* u     = dinv + N;
    float* wv    = u + N;
    float* s     = wv + N;
    float* s_prt = s + D_IN;
    float* part  = s_prt + (size_t)PS * D_IN;

    // only atomically-accumulated head buffers need zeroing (641 floats)
    hipMemsetAsync(d_ws, 0, 641 * sizeof(float), stream);

    int gn = (N + 255) / 256;

    // pass 1: deg by col -> dinv
    k_scatter<<<RSC, 256, 0, stream>>>(col, row, w, dinv, u, part, E, N, 0);
    k_red_deg<<<gn, 256, 0, stream>>>(part, dinv, N);
    // pass 2: p by row (gather dinv at col) -> u, S_u
    k_scatter<<<RSC, 256, 0, stream>>>(row, col, w, dinv, u, part, E, N, 1);
    k_red_u<<<gn, 256, 0, stream>>>(part, dinv, u, S_u, N);
    // pass 3: q by row (gather dinv*u at col) -> wv
    k_scatter<<<RSC, 256, 0, stream>>>(row, col, w, dinv, u, part, E, N, 2);
    k_red_wv<<<gn, 256, 0, stream>>>(part, dinv, u, wv, N);
    // feature contraction
    k_s<<<PS, 256, 0, stream>>>(x, wv, s_prt, N);
    k_sred<<<1, D_IN, 0, stream>>>(s_prt, s);
    // dense head
    k_h1<<<16, D_HID, 0, stream>>>(s, S_u, W1, b1, t1);
    k_h2<<<32, D_HID, 0, stream>>>(t1, W2, g_raw);
    k_h3<<<16, D_DENSE, 0, stream>>>(g_raw, b2, Wd1, z_raw, 1.0f / (float)N);
    k_h4<<<1, D_DENSE, 0, stream>>>(z_raw, bd1, Wd2, bd2, out);
}

// Round 4
// 151.875 us; speedup vs baseline: 1.7148x; 1.4096x over previous
//
#include <hip/hip_runtime.h>
#include <hip/hip_bf16.h>

// GCN forward, algebraically collapsed (no nonlinearity between convs, mean pool):
//   g = (1/n) * ( (A^T u)^T X ) @ W1 @ W2 + (1/n)*(sum u)*(b1 @ W2) + b2
// where A = D^{-1/2}(Adj+I)D^{-1/2}, u^T = 1^T A.  Head: softmax(relu(g@Wd1+bd1)@Wd2+bd2).
//
// Round 4: round-3 scatter was LATENCY-STARVED (1 block/CU = 4 waves, ~40
// serial 900-cyc edge iterations per thread => ~35us). Now: 256 blocks x 1024
// threads (16 waves/CU), <=3 edge iters per thread per range; folds read the
// 256 replicas with 32 unrolled independent loads/thread. Zero global atomics
// anywhere (head uses partial buffers folded by the consumer stage). No memset.

#define D_IN 128
#define D_HID 256
#define D_DENSE 128
#define NB 16384      // LDS histogram bins (floats) = 64 KB
#define RSC 256       // scatter blocks == partial replica count
#define FOLD_C 80     // nodes folded per k_red block  (250 blocks for N=20000)

// ---- privatized edge scatter: 256 blocks x 1024 threads --------------------
// mode 0: partial[b][col[e]] += w[e]
// mode 1: partial[b][row[e]] += w[e]*dinv[col[e]]
// mode 2: partial[b][row[e]] += w[e]*dinv[col[e]]*u[col[e]]
__global__ __launch_bounds__(1024) void k_scatter(
    const int* __restrict__ tgt, const int* __restrict__ src,
    const float* __restrict__ w, const float* __restrict__ dinv,
    const float* __restrict__ u, float* __restrict__ partial,
    int E, int N, int mode) {
    __shared__ float acc[NB];
    int per = (E + gridDim.x - 1) / gridDim.x;
    int e0 = blockIdx.x * per;
    int e1 = min(e0 + per, E);
    float* out = partial + (size_t)blockIdx.x * N;
    for (int base = 0; base < N; base += NB) {
        int lim = min(NB, N - base);
        for (int i = threadIdx.x; i < lim; i += 1024) acc[i] = 0.f;
        __syncthreads();
        for (int e = e0 + threadIdx.x; e < e1; e += 1024) {
            int t = tgt[e] - base;
            if ((unsigned)t < (unsigned)lim) {
                float v = w[e];
                if (mode != 0) {
                    int c = src[e];
                    float dc = dinv[c];
                    v *= (mode == 2) ? dc * u[c] : dc;
                }
                atomicAdd(&acc[t], v);     // LDS atomic
            }
        }
        __syncthreads();
        for (int i = threadIdx.x; i < lim; i += 1024) out[base + i] = acc[i];
        __syncthreads();
    }
}

// ---- fold 256 replicas + node math; 250 blocks x 1024 ----------------------
// thread = (rg in [0,8), j in [0,128)); node i = b*FOLD_C + j, replicas rg*32..+32
__global__ __launch_bounds__(1024) void k_red(
    const float* __restrict__ partial, float* __restrict__ dinv,
    float* __restrict__ u, float* __restrict__ wv,
    float* __restrict__ S_u_part, int N, int mode) {
    int j  = threadIdx.x & 127;
    int rg = threadIdx.x >> 7;
    int i  = blockIdx.x * FOLD_C + j;
    bool act = (j < FOLD_C) && (i < N);
    float s = 0.f;
    if (act) {
        const float* p = partial + (size_t)(rg * 32) * N + i;
        #pragma unroll
        for (int r = 0; r < 32; ++r) s += p[(size_t)r * N];
    }
    __shared__ float sh[8][128];
    sh[rg][j] = s;
    __syncthreads();
    if (rg == 0) {
        float tot = sh[0][j] + sh[1][j] + sh[2][j] + sh[3][j]
                  + sh[4][j] + sh[5][j] + sh[6][j] + sh[7][j];
        float ui = 0.f;
        if (act) {
            if (mode == 0) {
                dinv[i] = rsqrtf(tot + 1.0f);          // +1: self-loop weight
            } else if (mode == 1) {
                float d = dinv[i];
                ui = d * (tot + d);                     // self-loop dinv^2
                u[i] = ui;
            } else {
                float d = dinv[i];
                wv[i] = d * (tot + d * u[i]);           // self-loop dinv^2*u
            }
        }
        sh[0][j] = ui;                                  // own column only
    }
    __syncthreads();
    if (mode == 1) {                                    // uniform branch
        float v = (threadIdx.x < 128) ? sh[0][threadIdx.x] : 0.f;
        for (int off = 32; off > 0; off >>= 1) v += __shfl_down(v, off, 64);
        __shared__ float ws2[16];
        int lane = threadIdx.x & 63, wid = threadIdx.x >> 6;
        if (lane == 0) ws2[wid] = v;
        __syncthreads();
        if (threadIdx.x == 0) {
            float t = 0.f;
            #pragma unroll
            for (int q = 0; q < 16; ++q) t += ws2[q];
            S_u_part[blockIdx.x] = t;
        }
    }
}

// ---- feature pass: s_part[b][k] = sum_{rows of b} wv[i]*x[i,k] -------------
__global__ __launch_bounds__(1024) void k_s(
    const float* __restrict__ x, const float* __restrict__ wv,
    float* __restrict__ s_part, int n) {
    int k = threadIdx.x & 127, h = threadIdx.x >> 7;   // 8 rows x 128 cols
    float acc = 0.f;
    for (int i = blockIdx.x * 8 + h; i < n; i += 2048)
        acc += wv[i] * x[(size_t)i * D_IN + k];
    __shared__ float sh[8][128];
    sh[h][k] = acc;
    __syncthreads();
    if (h == 0) {
        float t = sh[0][k] + sh[1][k] + sh[2][k] + sh[3][k]
                + sh[4][k] + sh[5][k] + sh[6][k] + sh[7][k];
        s_part[blockIdx.x * D_IN + k] = t;
    }
}

// ---- fold s_part (256x128) -> s, S_u_part (nred) -> S_u; 1 block x 1024 ----
__global__ __launch_bounds__(1024) void k_sfold(
    const float* __restrict__ s_part, const float* __restrict__ S_u_part,
    float* __restrict__ s, float* __restrict__ S_u, int nred) {
    int k = threadIdx.x & 127, pg = threadIdx.x >> 7;  // 8 groups x 32 parts
    float acc = 0.f;
    #pragma unroll
    for (int q = 0; q < 32; ++q) acc += s_part[(pg * 32 + q) * D_IN + k];
    __shared__ float sh[8][128];
    sh[pg][k] = acc;
    __syncthreads();
    if (pg == 0) {
        float t = sh[0][k] + sh[1][k] + sh[2][k] + sh[3][k]
                + sh[4][k] + sh[5][k] + sh[6][k] + sh[7][k];
        s[k] = t;
    }
    // S_u fold
    float v = (threadIdx.x < nred) ? S_u_part[threadIdx.x] : 0.f;
    for (int off = 32; off > 0; off >>= 1) v += __shfl_down(v, off, 64);
    __shared__ float ws2[16];
    int lane = threadIdx.x & 63, wid = threadIdx.x >> 6;
    if (lane == 0) ws2[wid] = v;
    __syncthreads();
    if (threadIdx.x == 0) {
        float t = 0.f;
        #pragma unroll
        for (int q = 0; q < 16; ++q) t += ws2[q];
        S_u[0] = t;
    }
}

// ---- head 1: t1_part[b][t] = sum_{k in chunk8} s[k]W1[k][t] (+S_u*b1) ------
__global__ void k_h1(const float* __restrict__ s, const float* __restrict__ S_u,
                     const float* __restrict__ W1, const float* __restrict__ b1,
                     float* __restrict__ t1_part) {
    int t = threadIdx.x, b = blockIdx.x;               // 16 x 256
    float acc = 0.f;
    #pragma unroll
    for (int kk = 0; kk < 8; kk++) {
        int k = b * 8 + kk;
        acc += s[k] * W1[k * D_HID + t];
    }
    if (b == 0) acc += (*S_u) * b1[t];
    t1_part[b * D_HID + t] = acc;
}

// ---- head 2: fold t1 (16 parts), g_part[b][t] = sum_{k in chunk8} t1[k]W2 --
__global__ void k_h2(const float* __restrict__ t1_part, const float* __restrict__ W2,
                     float* __restrict__ g_part) {
    int t = threadIdx.x, b = blockIdx.x;               // 32 x 256
    __shared__ float t1v[8];
    if (t < 8) {
        int k = b * 8 + t;
        float a = 0.f;
        #pragma unroll
        for (int p = 0; p < 16; ++p) a += t1_part[p * D_HID + k];
        t1v[t] = a;
    }
    __syncthreads();
    float acc = 0.f;
    #pragma unroll
    for (int kk = 0; kk < 8; kk++)
        acc += t1v[kk] * W2[(b * 8 + kk) * D_HID + t];
    g_part[b * D_HID + t] = acc;
}

// ---- head 3: fold g (32 parts), z_part = (g/n+b2)@Wd1 ----------------------
__global__ void k_h3(const float* __restrict__ g_part, const float* __restrict__ b2,
                     const float* __restrict__ Wd1, float* __restrict__ z_part,
                     float inv_n) {
    int t = threadIdx.x, b = blockIdx.x;               // 16 x 128
    __shared__ float gv[16];
    if (t < 16) {
        int k = b * 16 + t;
        float a = 0.f;
        #pragma unroll
        for (int p = 0; p < 32; ++p) a += g_part[p * D_HID + k];
        gv[t] = a * inv_n + b2[k];
    }
    __syncthreads();
    float acc = 0.f;
    #pragma unroll
    for (int kk = 0; kk < 16; kk++)
        acc += gv[kk] * Wd1[(b * 16 + kk) * D_DENSE + t];
    z_part[b * D_DENSE + t] = acc;
}

// ---- head 4: fold z (16 parts), relu, logits, softmax ----------------------
__global__ void k_h4(const float* __restrict__ z_part, const float* __restrict__ bd1,
                     const float* __restrict__ Wd2, const float* __restrict__ bd2,
                     float* __restrict__ out) {
    int t = threadIdx.x;                               // 1 x 128
    float zr = bd1[t];
    #pragma unroll
    for (int p = 0; p < 16; ++p) zr += z_part[p * D_DENSE + t];
    float zt = fmaxf(zr, 0.f);
    float p0 = zt * Wd2[t * 2 + 0];
    float p1 = zt * Wd2[t * 2 + 1];
    for (int off = 32; off > 0; off >>= 1) {
        p0 += __shfl_down(p0, off, 64);
        p1 += __shfl_down(p1, off, 64);
    }
    __shared__ float s0[2], s1[2];
    int lane = t & 63, wid = t >> 6;
    if (lane == 0) { s0[wid] = p0; s1[wid] = p1; }
    __syncthreads();
    if (t == 0) {
        float l0 = s0[0] + s0[1] + bd2[0];
        float l1 = s1[0] + s1[1] + bd2[1];
        float m = fmaxf(l0, l1);
        float e0 = expf(l0 - m), e1 = expf(l1 - m);
        float inv = 1.0f / (e0 + e1);
        out[0] = e0 * inv;
        out[1] = e1 * inv;
    }
}

extern "C" void kernel_launch(void* const* d_in, const int* in_sizes, int n_in,
                              void* d_out, int out_size, void* d_ws, size_t ws_size,
                              hipStream_t stream) {
    const float* x   = (const float*)d_in[0];
    const int*   ei  = (const int*)  d_in[1];
    const float* w   = (const float*)d_in[2];
    const float* W1  = (const float*)d_in[3];
    const float* b1  = (const float*)d_in[4];
    const float* W2  = (const float*)d_in[5];
    const float* b2  = (const float*)d_in[6];
    const float* Wd1 = (const float*)d_in[7];
    const float* bd1 = (const float*)d_in[8];
    const float* Wd2 = (const float*)d_in[9];
    const float* bd2 = (const float*)d_in[10];
    float* out = (float*)d_out;

    const int N = in_sizes[0] / D_IN;      // 20000
    const int E = in_sizes[1] / 2;         // 640000
    const int* row = ei;
    const int* col = ei + E;
    const int nred = (N + FOLD_C - 1) / FOLD_C;   // 250

    // workspace layout (floats); everything is written before it is read,
    // so no zero-init / memset node is needed.
    float* ws     = (float*)d_ws;
    float* part   = ws;                                   // RSC*N
    float* dinv   = part + (size_t)RSC * N;               // N
    float* u      = dinv + N;                             // N
    float* wv     = u + N;                                // N
    float* s_prt  = wv + N;                               // RSC*128
    float* s      = s_prt + (size_t)RSC * D_IN;           // 128
    float* S_u_p  = s + D_IN;                             // nred (<=256)
    float* S_u    = S_u_p + 256;                          // 1
    float* t1_prt = S_u + 1;                              // 16*256
    float* g_prt  = t1_prt + 16 * D_HID;                  // 32*256
    float* z_prt  = g_prt + 32 * D_HID;                   // 16*128

    // pass 1: deg by col -> dinv
    k_scatter<<<RSC, 1024, 0, stream>>>(col, row, w, dinv, u, part, E, N, 0);
    k_red<<<nred, 1024, 0, stream>>>(part, dinv, u, wv, S_u_p, N, 0);
    // pass 2: by row, gather dinv[col] -> u, S_u partials
    k_scatter<<<RSC, 1024, 0, stream>>>(row, col, w, dinv, u, part, E, N, 1);
    k_red<<<nred, 1024, 0, stream>>>(part, dinv, u, wv, S_u_p, N, 1);
    // pass 3: by row, gather dinv[col]*u[col] -> wv
    k_scatter<<<RSC, 1024, 0, stream>>>(row, col, w, dinv, u, part, E, N, 2);
    k_red<<<nred, 1024, 0, stream>>>(part, dinv, u, wv, S_u_p, N, 2);
    // feature contraction + folds
    k_s<<<RSC, 1024, 0, stream>>>(x, wv, s_prt, N);
    k_sfold<<<1, 1024, 0, stream>>>(s_prt, S_u_p, s, S_u, nred);
    // dense head (partial buffers, no atomics)
    k_h1<<<16, D_HID, 0, stream>>>(s, S_u, W1, b1, t1_prt);
    k_h2<<<32, D_HID, 0, stream>>>(t1_prt, W2, g_prt);
    k_h3<<<16, D_DENSE, 0, stream>>>(g_prt, b2, Wd1, z_prt, 1.0f / (float)N);
    k_h4<<<1, D_DENSE, 0, stream>>>(z_prt, bd1, Wd2, bd2, out);
}